// Round 8
// baseline (171.049 us; speedup 1.0000x reference)
//
#include <hip/hip_runtime.h>
#include <cmath>

typedef unsigned int uint;
typedef unsigned long long ull;

#define BATCH 32
#define NA 8400
#define NC 80
#define MAXDET 100
#define NMSTHR 0.65f
#define SCTHR 0.01f

#define NT 1024         // NMS threads per block
#define NW (NT / 64)
#define EPT 9           // ceil(NA / NT)
#define NBINS 4096      // histogram bins on key[31:20]
#define CAP 512         // max candidates per sorted window

#define DGROUPS 132     // 64-anchor groups per image: 100 (L0) + 25 (L1) + 7 (L2)

__device__ __forceinline__ float stable_sigmoid(float x) {
    if (x >= 0.f) return 1.f / (1.f + expf(-x));
    float e = expf(x);
    return e / (1.f + e);
}

// ---------------- decode: one 256-thread block per 64 anchors (r7-EXACT) ----
// Wave w scans channels [20w, 20w+20) for the block's 64 consecutive anchors:
// every load is uniform-base + lane*4 -> ONE 256B contiguous segment per wave
// instruction. Per-wave (max, argmax) in registers with strict '>' (first
// max); 2KB LDS merge in ascending wave order -> exact jnp.argmax semantics.
// Wave 0 runs the reg/obj/box epilogue with unit-stride loads/stores.
// No atomics, no function tails (r4 regalloc lesson), no store->reload (r3).
template<int HW, int W, int S>
__device__ __forceinline__ void decode_blk(
    const float* __restrict__ cls, const float* __restrict__ reg,
    const float* __restrict__ obj, int b, int p0, int w, int lane, int ag0,
    float (*s_m)[64], int (*s_c)[64],
    float4* __restrict__ wboxes, int* __restrict__ wlabels, uint* __restrict__ wkeys)
{
    int p = p0 + lane;
    bool valid = (p < HW);            // only the last L2 group has invalid lanes
    int pc = valid ? p : (HW - 1);    // clamped for safe (dup) loads

    const float* cbase = cls + (size_t)b * NC * HW + (size_t)(w * 20) * HW + pc;
    float v[20];
    #pragma unroll
    for (int i = 0; i < 20; ++i) v[i] = cbase[(size_t)i * HW];
    float m = v[0]; int c = 0;
    #pragma unroll
    for (int i = 1; i < 20; ++i)
        if (v[i] > m) { m = v[i]; c = i; }     // strict > -> first max in slice

    s_m[w][lane] = m;
    s_c[w][lane] = c + w * 20;
    __syncthreads();

    if (w == 0) {
        float mm = s_m[0][lane]; int cc = s_c[0][lane];
        #pragma unroll
        for (int ww = 1; ww < 4; ++ww) {
            float om = s_m[ww][lane]; int oc = s_c[ww][lane];
            if (om > mm) { mm = om; cc = oc; } // strict > keeps lowest channel
        }
        const float* rb = reg + (size_t)b * 4 * HW + pc;
        float r0 = rb[0];
        float r1 = rb[HW];
        float r2 = rb[2 * (size_t)HW];
        float r3 = rb[3 * (size_t)HW];
        float ov = obj[(size_t)b * HW + pc];

        int y = pc / W;               // W constexpr -> magic mul
        int x = pc - y * W;
        float sc = stable_sigmoid(mm) * stable_sigmoid(ov);
        float cx = r0 * (float)S + (float)x * (float)S;
        float cy = r1 * (float)S + (float)y * (float)S;
        float bw = expf(r2) * (float)S;
        float bh = expf(r3) * (float)S;

        if (valid) {
            int ag = ag0 + lane;
            wboxes[ag]  = make_float4(cx - bw * 0.5f, cy - bh * 0.5f,
                                      cx + bw * 0.5f, cy + bh * 0.5f);
            wlabels[ag] = cc;
            wkeys[ag]   = (sc >= SCTHR) ? ~__float_as_uint(sc) : 0xFFFFFFFFu;
        }
    }
}

__global__ __launch_bounds__(256) void decode_kernel(
    const float* __restrict__ cls0, const float* __restrict__ reg0, const float* __restrict__ obj0,
    const float* __restrict__ cls1, const float* __restrict__ reg1, const float* __restrict__ obj1,
    const float* __restrict__ cls2, const float* __restrict__ reg2, const float* __restrict__ obj2,
    float4* __restrict__ wboxes, int* __restrict__ wlabels, uint* __restrict__ wkeys)
{
    __shared__ float s_m[4][64];
    __shared__ int   s_c[4][64];

    int bid  = blockIdx.x;            // BATCH * DGROUPS blocks
    int b    = bid / DGROUPS;         // literal divisor -> magic mul
    int g    = bid - b * DGROUPS;
    int t    = threadIdx.x;
    int w    = t >> 6;
    int lane = t & 63;

    if (g < 100) {
        int p0 = g * 64;
        decode_blk<6400, 80, 8>(cls0, reg0, obj0, b, p0, w, lane,
                                b * NA + p0, s_m, s_c, wboxes, wlabels, wkeys);
    } else if (g < 125) {
        int p0 = (g - 100) * 64;
        decode_blk<1600, 40, 16>(cls1, reg1, obj1, b, p0, w, lane,
                                 b * NA + 6400 + p0, s_m, s_c, wboxes, wlabels, wkeys);
    } else {
        int p0 = (g - 125) * 64;
        decode_blk<400, 20, 32>(cls2, reg2, obj2, b, p0, w, lane,
                                b * NA + 8000 + p0, s_m, s_c, wboxes, wlabels, wkeys);
    }
}

// ---------------- NMS: sorted windows + chunk-local mask walk --------------
// vs r5/r7 (48.4 us): (1) amax sweep fused into hist sweep (one fewer 9-iter
// global pass, r6-proven); (2) the serial wave-0 walk builds a 64x64
// chunk-local suppression mask via a UNIFORM loop (LDS broadcast reads, all
// 64 lanes in parallel), then accepts via pure bitmath: ballot + ffs +
// lane-f direct LDS write -- no per-accept shfl broadcasts. Exact greedy:
// bit f is consulted only when candidate f is accepted; IoU expression is
// textually identical to the reference. (r6's failure was building ALL
// 512x512 pairs through per-wave LDS-latency chains; this builds only the
// ~2 chunks the walk actually touches.)
__global__ __launch_bounds__(NT) void nms_kernel(
    const float4* __restrict__ wboxes, const int* __restrict__ wlabels,
    const uint* __restrict__ wkeys, float* __restrict__ out)
{
    int b = blockIdx.x;
    int t = threadIdx.x;
    int lane = t & 63;
    int wv = t >> 6;
    const float4* boxes  = wboxes  + (size_t)b * NA;
    const int*    labels = wlabels + (size_t)b * NA;
    const uint*   keys   = wkeys   + (size_t)b * NA;

    __shared__ uint   s_hist[NBINS];
    __shared__ uint   s_cum[NBINS + 1];    // exclusive prefix
    __shared__ uint   s_wsum[NW];
    __shared__ ull    s_skey[CAP];
    __shared__ float4 s_cbox[CAP];         // candidate OFFSET boxes (prefetched)
    __shared__ float  s_ca[CAP];           // candidate offset-box areas
    __shared__ int    s_clb[CAP];          // candidate labels
    __shared__ float  s_kbox[MAXDET][4];   // kept OFFSET boxes
    __shared__ float  s_ka1[MAXDET];
    __shared__ int    s_kidx[MAXDET];
    __shared__ float  s_kscr[MAXDET];
    __shared__ int    s_klab[MAXDET];
    __shared__ float  s_red[NW];
    __shared__ float  s_off;
    __shared__ int    s_kept, s_winlo, s_winhi, s_nsel;

    // ---- zero hist; FUSED sweep: max|coord| + key histogram (r6-proven) ----
    for (int i = t; i < NBINS; i += NT) s_hist[i] = 0;
    if (t == 0) { s_kept = 0; s_winlo = 0; }
    __syncthreads();
    float m = 0.f;
    #pragma unroll
    for (int w = 0; w < EPT; ++w) {
        int e = t + w * NT;
        if (e < NA) {
            float4 v = boxes[e];
            m = fmaxf(m, fmaxf(fmaxf(fabsf(v.x), fabsf(v.y)),
                               fmaxf(fabsf(v.z), fabsf(v.w))));
            uint k = keys[e];
            if (k != 0xFFFFFFFFu) atomicAdd(&s_hist[k >> 20], 1u);
        }
    }
    #pragma unroll
    for (int o = 32; o >= 1; o >>= 1) m = fmaxf(m, __shfl_xor(m, o));
    if (lane == 0) s_red[wv] = m;
    __syncthreads();
    if (t == 0) {
        float mm = 0.f;
        for (int w = 0; w < NW; ++w) mm = fmaxf(mm, s_red[w]);
        s_off = mm + 1.f;
    }

    // ---- exclusive scan over 4096 bins: 4 bins/thread + shfl scans ----
    uint l0 = s_hist[4 * t], l1 = s_hist[4 * t + 1],
         l2 = s_hist[4 * t + 2], l3 = s_hist[4 * t + 3];
    uint L = l0 + l1 + l2 + l3;
    uint ls = L;
    #pragma unroll
    for (int o = 1; o < 64; o <<= 1) {
        uint v = __shfl_up(ls, o);
        if (lane >= o) ls += v;
    }
    if (lane == 63) s_wsum[wv] = ls;
    __syncthreads();
    if (t < NW) {
        uint v = s_wsum[t];
        uint vs = v;
        #pragma unroll
        for (int o = 1; o < NW; o <<= 1) {
            uint u = __shfl_up(vs, o);
            if ((t & 63) >= o) vs += u;
        }
        s_wsum[t] = vs - v;
    }
    __syncthreads();
    uint base = s_wsum[wv] + (ls - L);
    s_cum[4 * t]     = base;
    s_cum[4 * t + 1] = base + l0;
    s_cum[4 * t + 2] = base + l0 + l1;
    s_cum[4 * t + 3] = base + l0 + l1 + l2;
    if (t == NT - 1) s_cum[NBINS] = base + L;
    float off;

    // ---- window loop (typically runs once) ----
    for (;;) {
        __syncthreads();
        int kept = s_kept, winlo = s_winlo;
        uint remaining = s_cum[NBINS] - s_cum[winlo];
        if (kept >= MAXDET || winlo >= NBINS || remaining == 0u) break;
        if (t == 0) { s_winhi = winlo + 1; s_nsel = 0; }   // giant-bin clamp floor
        if (t < CAP) s_skey[t] = ~0ull;
        __syncthreads();
        // winhi via unique-boundary store: pred(i) = cum[i+1]-cl <= CAP is
        // monotone non-increasing in i, so exactly one i has pred(i) && !pred(i+1).
        uint cl = s_cum[winlo];
        #pragma unroll
        for (int q = 0; q < 4; ++q) {
            int i = t + q * NT;
            if (i >= winlo && i < NBINS) {
                bool p0 = (s_cum[i + 1] - cl) <= (uint)CAP;
                bool p1 = (i + 1 < NBINS) && ((s_cum[i + 2] - cl) <= (uint)CAP);
                if (p0 && !p1) s_winhi = i + 1;   // unique writer
            }
        }
        __syncthreads();
        int winhi = s_winhi;

        // wave-aggregated compaction of window candidates (keys from global, L2-hot)
        #pragma unroll
        for (int w = 0; w < EPT; ++w) {
            int e = t + w * NT;
            bool q = false;
            uint k = 0;
            if (e < NA) {
                k = keys[e];
                if (k != 0xFFFFFFFFu) {
                    int bin = (int)(k >> 20);
                    q = (bin >= winlo && bin < winhi);
                }
            }
            ull mask = __ballot(q);
            if (mask) {
                int leader = __ffsll(mask) - 1;
                int pbase = 0;
                if (lane == leader) pbase = atomicAdd(&s_nsel, __popcll(mask));
                pbase = __shfl(pbase, leader);
                if (q) {
                    int pos = pbase + __popcll(mask & ((1ull << lane) - 1ull));
                    if (pos < CAP) s_skey[pos] = ((ull)k << 32) | (uint)e;
                }
            }
        }
        __syncthreads();
        int nsel = s_nsel; if (nsel > CAP) nsel = CAP;

        // hybrid bitonic sort of CAP=512 ull keys ascending: j<64 passes are
        // intra-wave shfl_xor (no barrier); j>=64 via LDS (6 barriered passes).
        ull k = (t < CAP) ? s_skey[t] : ~0ull;
        for (int k2 = 2; k2 <= CAP; k2 <<= 1) {
            for (int j = k2 >> 1; j > 0; j >>= 1) {
                if (j >= 64) {
                    if (t < CAP) s_skey[t] = k;
                    __syncthreads();
                    if (t < CAP) {
                        ull kp = s_skey[t ^ j];
                        bool low = (t & j) == 0;
                        bool up  = (t & k2) == 0;
                        k = ((k < kp) == (low == up)) ? k : kp;
                    }
                    __syncthreads();
                } else if (t < CAP) {
                    ull kp = __shfl_xor(k, j);
                    bool low = (t & j) == 0;
                    bool up  = (t & k2) == 0;
                    k = ((k < kp) == (low == up)) ? k : kp;
                }
            }
        }
        if (t < CAP) s_skey[t] = k;
        __syncthreads();

        // parallel candidate prefetch: scattered global reads done ONCE by
        // all 1024 threads; everything below touches only LDS.
        off = s_off;
        if (t < nsel) {
            ull sk = s_skey[t];
            if (sk != ~0ull) {
                int idx = (int)(sk & 0xFFFFFFFFull);
                float4 rb = boxes[idx];
                int lb = labels[idx];
                float lo = (float)lb * off;
                float c0 = rb.x + lo, c1 = rb.y + lo;
                float c2 = rb.z + lo, c3 = rb.w + lo;
                s_cbox[t] = make_float4(c0, c1, c2, c3);
                s_ca[t]   = (c2 - c0) * (c3 - c1);
                s_clb[t]  = lb;
            }
        }
        __syncthreads();

        // ---- walk on wave 0: chunk-local mask + bitmath accept loop ----
        if (t < 64) {
            int kept2 = s_kept;
            for (int cb = 0; cb < nsel && kept2 < MAXDET; cb += 64) {
                int ci = cb + lane;
                ull sk = (ci < nsel) ? s_skey[ci] : ~0ull;
                bool alive = (sk != ~0ull);
                int idx = 0, lab = 0;
                float sc = 0.f, c0 = 0.f, c1 = 0.f, c2 = 0.f, c3 = 0.f, ca = 0.f;
                if (alive) {
                    idx = (int)(sk & 0xFFFFFFFFull);
                    sc  = __uint_as_float(~(uint)(sk >> 32));   // exact score bits
                    float4 cbx = s_cbox[ci];
                    c0 = cbx.x; c1 = cbx.y; c2 = cbx.z; c3 = cbx.w;
                    ca = s_ca[ci];
                    lab = s_clb[ci];
                    // vs already-kept (prior windows + prior chunks)
                    for (int q = 0; q < kept2; ++q) {
                        float tlx = fmaxf(s_kbox[q][0], c0);
                        float tly = fmaxf(s_kbox[q][1], c1);
                        float brx = fminf(s_kbox[q][2], c2);
                        float bry = fminf(s_kbox[q][3], c3);
                        float ww = fmaxf(brx - tlx, 0.f);
                        float hh = fmaxf(bry - tly, 0.f);
                        float inter = ww * hh;
                        float iou = inter / (s_ka1[q] + ca - inter + 1e-6f);
                        if (iou > NMSTHR) { alive = false; break; }
                    }
                }
                // chunk-local suppression mask: bit i = "if candidate cb+i is
                // accepted, it suppresses me" (only i < lane consulted).
                // Uniform loop -> s_cbox[cb+i]/s_ca[cb+i] are LDS broadcasts.
                ull supmask = 0ull;
                int lim = nsel - cb; if (lim > 64) lim = 64;
                for (int i = 0; i < lim; ++i) {
                    float4 bi = s_cbox[cb + i];
                    float  ai = s_ca[cb + i];
                    float tlx = fmaxf(bi.x, c0), tly = fmaxf(bi.y, c1);
                    float brx = fminf(bi.z, c2), bry = fminf(bi.w, c3);
                    float ww = fmaxf(brx - tlx, 0.f), hh = fmaxf(bry - tly, 0.f);
                    float inter = ww * hh;
                    float iou = inter / (ai + ca - inter + 1e-6f);
                    if (i < lane && iou > NMSTHR) supmask |= (1ull << i);
                }
                // bitmath accept loop: ballot + ffs + lane-f direct LDS write
                ull am = __ballot(alive);
                while (am != 0ull && kept2 < MAXDET) {
                    int f = __ffsll(am) - 1;
                    if (lane == f) {
                        s_kbox[kept2][0] = c0; s_kbox[kept2][1] = c1;
                        s_kbox[kept2][2] = c2; s_kbox[kept2][3] = c3;
                        s_ka1[kept2] = ca; s_kidx[kept2] = idx;
                        s_kscr[kept2] = sc; s_klab[kept2] = lab;
                        alive = false;
                    }
                    kept2++;
                    if (alive && ((supmask >> f) & 1ull)) alive = false;
                    am = __ballot(alive);
                }
            }
            if (lane == 0) s_kept = kept2;
        }
        __syncthreads();
        if (t == 0) s_winlo = s_winhi;
    }
    __syncthreads();

    // ---- epilogue: boxes/scores/labels/valid (fp32) ----
    if (t < MAXDET) {
        int kept = s_kept;
        float4 obx = make_float4(0.f, 0.f, 0.f, 0.f);
        float osc = 0.f, olab = -1.f, oval = 0.f;
        if (t < kept) {
            int idx = s_kidx[t];
            obx  = boxes[idx];              // raw (non-offset) box
            osc  = s_kscr[t];
            olab = (float)s_klab[t];
            oval = 1.f;
        }
        float* ob = out + ((size_t)b * MAXDET + t) * 4;
        ob[0] = obx.x; ob[1] = obx.y; ob[2] = obx.z; ob[3] = obx.w;
        out[BATCH * MAXDET * 4 + b * MAXDET + t] = osc;
        out[BATCH * MAXDET * 5 + b * MAXDET + t] = olab;
        out[BATCH * MAXDET * 6 + b * MAXDET + t] = oval;
    }
}

extern "C" void kernel_launch(void* const* d_in, const int* in_sizes, int n_in,
                              void* d_out, int out_size, void* d_ws, size_t ws_size,
                              hipStream_t stream) {
    // setup_inputs() dict order: cls0, reg0, obj0, cls1, reg1, obj1, cls2, reg2, obj2
    const float* cls0 = (const float*)d_in[0];
    const float* reg0 = (const float*)d_in[1];
    const float* obj0 = (const float*)d_in[2];
    const float* cls1 = (const float*)d_in[3];
    const float* reg1 = (const float*)d_in[4];
    const float* obj1 = (const float*)d_in[5];
    const float* cls2 = (const float*)d_in[6];
    const float* reg2 = (const float*)d_in[7];
    const float* obj2 = (const float*)d_in[8];

    // ws layout: boxes | labels | keys
    char* ws = (char*)d_ws;
    size_t nBA = (size_t)BATCH * NA;
    float4* wboxes  = (float4*)ws;
    int*    wlabels = (int*)(ws + nBA * 16);
    uint*   wkeys   = (uint*)(ws + nBA * 20);

    decode_kernel<<<BATCH * DGROUPS, 256, 0, stream>>>(
        cls0, reg0, obj0, cls1, reg1, obj1, cls2, reg2, obj2,
        wboxes, wlabels, wkeys);

    nms_kernel<<<BATCH, NT, 0, stream>>>(wboxes, wlabels, wkeys, (float*)d_out);
}

// Round 9
// 165.192 us; speedup vs baseline: 1.0355x; 1.0355x over previous
//
#include <hip/hip_runtime.h>
#include <cmath>

typedef unsigned int uint;
typedef unsigned long long ull;

#define BATCH 32
#define NA 8400
#define NC 80
#define MAXDET 100
#define NMSTHR 0.65f
#define SCTHR 0.01f

#define NT 1024         // NMS threads per block
#define NW (NT / 64)
#define EPT 9           // ceil(NA / NT)
#define NBINS 4096      // histogram bins on key[31:20]
#define CAP 512         // max candidates per sorted window

#define DGROUPS 132     // 64-anchor groups per image: 100 (L0) + 25 (L1) + 7 (L2)

__device__ __forceinline__ float stable_sigmoid(float x) {
    if (x >= 0.f) return 1.f / (1.f + expf(-x));
    float e = expf(x);
    return e / (1.f + e);
}

// ---------------- decode: one 256-thread block per 64 anchors (r7-EXACT) ----
// Wave w scans channels [20w, 20w+20) for the block's 64 consecutive anchors:
// every load is uniform-base + lane*4 -> ONE 256B contiguous segment per wave
// instruction. Per-wave (max, argmax) in registers with strict '>' (first
// max); 2KB LDS merge in ascending wave order -> exact jnp.argmax semantics.
// Wave 0 runs the reg/obj/box epilogue with unit-stride loads/stores.
// No atomics, no function tails (r4 regalloc lesson), no store->reload (r3).
template<int HW, int W, int S>
__device__ __forceinline__ void decode_blk(
    const float* __restrict__ cls, const float* __restrict__ reg,
    const float* __restrict__ obj, int b, int p0, int w, int lane, int ag0,
    float (*s_m)[64], int (*s_c)[64],
    float4* __restrict__ wboxes, int* __restrict__ wlabels, uint* __restrict__ wkeys)
{
    int p = p0 + lane;
    bool valid = (p < HW);            // only the last L2 group has invalid lanes
    int pc = valid ? p : (HW - 1);    // clamped for safe (dup) loads

    const float* cbase = cls + (size_t)b * NC * HW + (size_t)(w * 20) * HW + pc;
    float v[20];
    #pragma unroll
    for (int i = 0; i < 20; ++i) v[i] = cbase[(size_t)i * HW];
    float m = v[0]; int c = 0;
    #pragma unroll
    for (int i = 1; i < 20; ++i)
        if (v[i] > m) { m = v[i]; c = i; }     // strict > -> first max in slice

    s_m[w][lane] = m;
    s_c[w][lane] = c + w * 20;
    __syncthreads();

    if (w == 0) {
        float mm = s_m[0][lane]; int cc = s_c[0][lane];
        #pragma unroll
        for (int ww = 1; ww < 4; ++ww) {
            float om = s_m[ww][lane]; int oc = s_c[ww][lane];
            if (om > mm) { mm = om; cc = oc; } // strict > keeps lowest channel
        }
        const float* rb = reg + (size_t)b * 4 * HW + pc;
        float r0 = rb[0];
        float r1 = rb[HW];
        float r2 = rb[2 * (size_t)HW];
        float r3 = rb[3 * (size_t)HW];
        float ov = obj[(size_t)b * HW + pc];

        int y = pc / W;               // W constexpr -> magic mul
        int x = pc - y * W;
        float sc = stable_sigmoid(mm) * stable_sigmoid(ov);
        float cx = r0 * (float)S + (float)x * (float)S;
        float cy = r1 * (float)S + (float)y * (float)S;
        float bw = expf(r2) * (float)S;
        float bh = expf(r3) * (float)S;

        if (valid) {
            int ag = ag0 + lane;
            wboxes[ag]  = make_float4(cx - bw * 0.5f, cy - bh * 0.5f,
                                      cx + bw * 0.5f, cy + bh * 0.5f);
            wlabels[ag] = cc;
            wkeys[ag]   = (sc >= SCTHR) ? ~__float_as_uint(sc) : 0xFFFFFFFFu;
        }
    }
}

__global__ __launch_bounds__(256) void decode_kernel(
    const float* __restrict__ cls0, const float* __restrict__ reg0, const float* __restrict__ obj0,
    const float* __restrict__ cls1, const float* __restrict__ reg1, const float* __restrict__ obj1,
    const float* __restrict__ cls2, const float* __restrict__ reg2, const float* __restrict__ obj2,
    float4* __restrict__ wboxes, int* __restrict__ wlabels, uint* __restrict__ wkeys)
{
    __shared__ float s_m[4][64];
    __shared__ int   s_c[4][64];

    int bid  = blockIdx.x;            // BATCH * DGROUPS blocks
    int b    = bid / DGROUPS;         // literal divisor -> magic mul
    int g    = bid - b * DGROUPS;
    int t    = threadIdx.x;
    int w    = t >> 6;
    int lane = t & 63;

    if (g < 100) {
        int p0 = g * 64;
        decode_blk<6400, 80, 8>(cls0, reg0, obj0, b, p0, w, lane,
                                b * NA + p0, s_m, s_c, wboxes, wlabels, wkeys);
    } else if (g < 125) {
        int p0 = (g - 100) * 64;
        decode_blk<1600, 40, 16>(cls1, reg1, obj1, b, p0, w, lane,
                                 b * NA + 6400 + p0, s_m, s_c, wboxes, wlabels, wkeys);
    } else {
        int p0 = (g - 125) * 64;
        decode_blk<400, 20, 32>(cls2, reg2, obj2, b, p0, w, lane,
                                b * NA + 8000 + p0, s_m, s_c, wboxes, wlabels, wkeys);
    }
}

// ---------------- NMS via sorted walk (r5 walk, fused front) ---------------
// vs r7 (48.4 us), two load-elimination changes, walk/sort UNTOUCHED:
// (1) amax sweep fused into the hist sweep (one 9-iter global pass, not two);
// (2) the 9 keys each thread loads are cached in registers (unrolled const
//     indexing -> stays in VGPRs), so the window-loop compaction re-reads
//     ZERO keys from global. r8's chunk-mask walk is reverted (cost +4.4).
__global__ __launch_bounds__(NT) void nms_kernel(
    const float4* __restrict__ wboxes, const int* __restrict__ wlabels,
    const uint* __restrict__ wkeys, float* __restrict__ out)
{
    int b = blockIdx.x;
    int t = threadIdx.x;
    int lane = t & 63;
    int wv = t >> 6;
    const float4* boxes  = wboxes  + (size_t)b * NA;
    const int*    labels = wlabels + (size_t)b * NA;
    const uint*   keys   = wkeys   + (size_t)b * NA;

    __shared__ uint   s_hist[NBINS];
    __shared__ uint   s_cum[NBINS + 1];    // exclusive prefix
    __shared__ uint   s_wsum[NW];
    __shared__ ull    s_skey[CAP];
    __shared__ float4 s_cbox[CAP];         // candidate OFFSET boxes (prefetched)
    __shared__ float  s_ca[CAP];           // candidate offset-box areas
    __shared__ int    s_clb[CAP];          // candidate labels
    __shared__ float  s_kbox[MAXDET][4];   // kept OFFSET boxes
    __shared__ float  s_ka1[MAXDET];
    __shared__ int    s_kidx[MAXDET];
    __shared__ float  s_kscr[MAXDET];
    __shared__ int    s_klab[MAXDET];
    __shared__ float  s_red[NW];
    __shared__ float  s_off;
    __shared__ int    s_kept, s_winlo, s_winhi, s_nsel;

    // ---- zero hist; FUSED sweep: max|coord| + key histogram + key cache ----
    for (int i = t; i < NBINS; i += NT) s_hist[i] = 0;
    if (t == 0) { s_kept = 0; s_winlo = 0; }
    __syncthreads();
    float m = 0.f;
    uint kreg[EPT];                        // per-thread key cache (const-indexed)
    #pragma unroll
    for (int w = 0; w < EPT; ++w) {
        int e = t + w * NT;
        kreg[w] = 0xFFFFFFFFu;
        if (e < NA) {
            float4 v = boxes[e];
            m = fmaxf(m, fmaxf(fmaxf(fabsf(v.x), fabsf(v.y)),
                               fmaxf(fabsf(v.z), fabsf(v.w))));
            uint k = keys[e];
            kreg[w] = k;
            if (k != 0xFFFFFFFFu) atomicAdd(&s_hist[k >> 20], 1u);
        }
    }
    #pragma unroll
    for (int o = 32; o >= 1; o >>= 1) m = fmaxf(m, __shfl_xor(m, o));
    if (lane == 0) s_red[wv] = m;
    __syncthreads();
    if (t == 0) {
        float mm = 0.f;
        for (int w = 0; w < NW; ++w) mm = fmaxf(mm, s_red[w]);
        s_off = mm + 1.f;
    }

    // ---- exclusive scan over 4096 bins: 4 bins/thread + shfl scans ----
    uint l0 = s_hist[4 * t], l1 = s_hist[4 * t + 1],
         l2 = s_hist[4 * t + 2], l3 = s_hist[4 * t + 3];
    uint L = l0 + l1 + l2 + l3;
    uint ls = L;
    #pragma unroll
    for (int o = 1; o < 64; o <<= 1) {
        uint v = __shfl_up(ls, o);
        if (lane >= o) ls += v;
    }
    if (lane == 63) s_wsum[wv] = ls;
    __syncthreads();
    if (t < NW) {
        uint v = s_wsum[t];
        uint vs = v;
        #pragma unroll
        for (int o = 1; o < NW; o <<= 1) {
            uint u = __shfl_up(vs, o);
            if ((t & 63) >= o) vs += u;
        }
        s_wsum[t] = vs - v;
    }
    __syncthreads();
    uint base = s_wsum[wv] + (ls - L);
    s_cum[4 * t]     = base;
    s_cum[4 * t + 1] = base + l0;
    s_cum[4 * t + 2] = base + l0 + l1;
    s_cum[4 * t + 3] = base + l0 + l1 + l2;
    if (t == NT - 1) s_cum[NBINS] = base + L;
    float off;

    // ---- window loop (typically runs once) ----
    for (;;) {
        __syncthreads();
        int kept = s_kept, winlo = s_winlo;
        uint remaining = s_cum[NBINS] - s_cum[winlo];
        if (kept >= MAXDET || winlo >= NBINS || remaining == 0u) break;
        if (t == 0) { s_winhi = winlo + 1; s_nsel = 0; }   // giant-bin clamp floor
        if (t < CAP) s_skey[t] = ~0ull;
        __syncthreads();
        // winhi via unique-boundary store: pred(i) = cum[i+1]-cl <= CAP is
        // monotone non-increasing in i, so exactly one i has pred(i) && !pred(i+1).
        uint cl = s_cum[winlo];
        #pragma unroll
        for (int q = 0; q < 4; ++q) {
            int i = t + q * NT;
            if (i >= winlo && i < NBINS) {
                bool p0 = (s_cum[i + 1] - cl) <= (uint)CAP;
                bool p1 = (i + 1 < NBINS) && ((s_cum[i + 2] - cl) <= (uint)CAP);
                if (p0 && !p1) s_winhi = i + 1;   // unique writer
            }
        }
        __syncthreads();
        int winhi = s_winhi;

        // wave-aggregated compaction of window candidates (keys from REGISTERS)
        #pragma unroll
        for (int w = 0; w < EPT; ++w) {
            int e = t + w * NT;
            uint k = kreg[w];
            bool q = false;
            if (k != 0xFFFFFFFFu) {
                int bin = (int)(k >> 20);
                q = (bin >= winlo && bin < winhi);
            }
            ull mask = __ballot(q);
            if (mask) {
                int leader = __ffsll(mask) - 1;
                int pbase = 0;
                if (lane == leader) pbase = atomicAdd(&s_nsel, __popcll(mask));
                pbase = __shfl(pbase, leader);
                if (q) {
                    int pos = pbase + __popcll(mask & ((1ull << lane) - 1ull));
                    if (pos < CAP) s_skey[pos] = ((ull)k << 32) | (uint)e;
                }
            }
        }
        __syncthreads();
        int nsel = s_nsel; if (nsel > CAP) nsel = CAP;

        // hybrid bitonic sort of CAP=512 ull keys ascending: j<64 passes are
        // intra-wave shfl_xor (no barrier); j>=64 via LDS (6 barriered passes).
        ull k = (t < CAP) ? s_skey[t] : ~0ull;
        for (int k2 = 2; k2 <= CAP; k2 <<= 1) {
            for (int j = k2 >> 1; j > 0; j >>= 1) {
                if (j >= 64) {
                    if (t < CAP) s_skey[t] = k;
                    __syncthreads();
                    if (t < CAP) {
                        ull kp = s_skey[t ^ j];
                        bool low = (t & j) == 0;
                        bool up  = (t & k2) == 0;
                        k = ((k < kp) == (low == up)) ? k : kp;
                    }
                    __syncthreads();
                } else if (t < CAP) {
                    ull kp = __shfl_xor(k, j);
                    bool low = (t & j) == 0;
                    bool up  = (t & k2) == 0;
                    k = ((k < kp) == (low == up)) ? k : kp;
                }
            }
        }
        if (t < CAP) s_skey[t] = k;
        __syncthreads();

        // parallel candidate prefetch: scattered global reads done ONCE by
        // all 1024 threads; the serial walk below touches only LDS.
        off = s_off;
        if (t < nsel) {
            ull sk = s_skey[t];
            if (sk != ~0ull) {
                int idx = (int)(sk & 0xFFFFFFFFull);
                float4 rb = boxes[idx];
                int lb = labels[idx];
                float lo = (float)lb * off;
                float c0 = rb.x + lo, c1 = rb.y + lo;
                float c2 = rb.z + lo, c3 = rb.w + lo;
                s_cbox[t] = make_float4(c0, c1, c2, c3);
                s_ca[t]   = (c2 - c0) * (c3 - c1);
                s_clb[t]  = lb;
            }
        }
        __syncthreads();

        // sorted walk on wave 0 (r5-EXACT: per-accept IoU + shfl broadcast)
        if (t < 64) {
            int kept2 = s_kept;
            for (int cb = 0; cb < nsel && kept2 < MAXDET; cb += 64) {
                int ci = cb + lane;
                ull sk = (ci < nsel) ? s_skey[ci] : ~0ull;
                bool has = (sk != ~0ull);
                int idx = 0, lab = 0;
                float sc = 0.f, c0 = 0.f, c1 = 0.f, c2 = 0.f, c3 = 0.f, ca = 0.f;
                if (has) {
                    idx = (int)(sk & 0xFFFFFFFFull);
                    sc  = __uint_as_float(~(uint)(sk >> 32));   // exact score bits
                    float4 cbx = s_cbox[ci];
                    c0 = cbx.x; c1 = cbx.y; c2 = cbx.z; c3 = cbx.w;
                    ca = s_ca[ci];
                    lab = s_clb[ci];
                    for (int q = 0; q < kept2; ++q) {
                        float tlx = fmaxf(s_kbox[q][0], c0);
                        float tly = fmaxf(s_kbox[q][1], c1);
                        float brx = fminf(s_kbox[q][2], c2);
                        float bry = fminf(s_kbox[q][3], c3);
                        float ww = fmaxf(brx - tlx, 0.f);
                        float hh = fmaxf(bry - tly, 0.f);
                        float inter = ww * hh;
                        float iou = inter / (s_ka1[q] + ca - inter + 1e-6f);
                        if (iou > NMSTHR) { has = false; break; }
                    }
                }
                ull am = __ballot(has);
                while (am && kept2 < MAXDET) {
                    int f = __ffsll(am) - 1;
                    float f0 = __shfl(c0, f), f1 = __shfl(c1, f);
                    float f2 = __shfl(c2, f), f3 = __shfl(c3, f);
                    float fa = __shfl(ca, f);
                    int   fidx = __shfl(idx, f);
                    int   flab = __shfl(lab, f);
                    float fsc  = __shfl(sc, f);
                    if (lane == 0) {
                        s_kbox[kept2][0] = f0; s_kbox[kept2][1] = f1;
                        s_kbox[kept2][2] = f2; s_kbox[kept2][3] = f3;
                        s_ka1[kept2] = fa; s_kidx[kept2] = fidx;
                        s_kscr[kept2] = fsc; s_klab[kept2] = flab;
                    }
                    kept2++;
                    if (lane == f) has = false;
                    if (has) {
                        float tlx = fmaxf(f0, c0), tly = fmaxf(f1, c1);
                        float brx = fminf(f2, c2), bry = fminf(f3, c3);
                        float ww = fmaxf(brx - tlx, 0.f), hh = fmaxf(bry - tly, 0.f);
                        float inter = ww * hh;
                        float iou = inter / (fa + ca - inter + 1e-6f);
                        if (iou > NMSTHR) has = false;
                    }
                    am = __ballot(has);
                }
            }
            if (lane == 0) s_kept = kept2;
        }
        __syncthreads();
        if (t == 0) s_winlo = s_winhi;
    }
    __syncthreads();

    // ---- epilogue: boxes/scores/labels/valid (fp32) ----
    if (t < MAXDET) {
        int kept = s_kept;
        float4 obx = make_float4(0.f, 0.f, 0.f, 0.f);
        float osc = 0.f, olab = -1.f, oval = 0.f;
        if (t < kept) {
            int idx = s_kidx[t];
            obx  = boxes[idx];              // raw (non-offset) box
            osc  = s_kscr[t];
            olab = (float)s_klab[t];
            oval = 1.f;
        }
        float* ob = out + ((size_t)b * MAXDET + t) * 4;
        ob[0] = obx.x; ob[1] = obx.y; ob[2] = obx.z; ob[3] = obx.w;
        out[BATCH * MAXDET * 4 + b * MAXDET + t] = osc;
        out[BATCH * MAXDET * 5 + b * MAXDET + t] = olab;
        out[BATCH * MAXDET * 6 + b * MAXDET + t] = oval;
    }
}

extern "C" void kernel_launch(void* const* d_in, const int* in_sizes, int n_in,
                              void* d_out, int out_size, void* d_ws, size_t ws_size,
                              hipStream_t stream) {
    // setup_inputs() dict order: cls0, reg0, obj0, cls1, reg1, obj1, cls2, reg2, obj2
    const float* cls0 = (const float*)d_in[0];
    const float* reg0 = (const float*)d_in[1];
    const float* obj0 = (const float*)d_in[2];
    const float* cls1 = (const float*)d_in[3];
    const float* reg1 = (const float*)d_in[4];
    const float* obj1 = (const float*)d_in[5];
    const float* cls2 = (const float*)d_in[6];
    const float* reg2 = (const float*)d_in[7];
    const float* obj2 = (const float*)d_in[8];

    // ws layout: boxes | labels | keys
    char* ws = (char*)d_ws;
    size_t nBA = (size_t)BATCH * NA;
    float4* wboxes  = (float4*)ws;
    int*    wlabels = (int*)(ws + nBA * 16);
    uint*   wkeys   = (uint*)(ws + nBA * 20);

    decode_kernel<<<BATCH * DGROUPS, 256, 0, stream>>>(
        cls0, reg0, obj0, cls1, reg1, obj1, cls2, reg2, obj2,
        wboxes, wlabels, wkeys);

    nms_kernel<<<BATCH, NT, 0, stream>>>(wboxes, wlabels, wkeys, (float*)d_out);
}

// Round 10
// 163.106 us; speedup vs baseline: 1.0487x; 1.0128x over previous
//
#include <hip/hip_runtime.h>
#include <cmath>

typedef unsigned int uint;
typedef unsigned long long ull;

#define BATCH 32
#define NA 8400
#define NC 80
#define MAXDET 100
#define NMSTHR 0.65f
#define SCTHR 0.01f

#define NT 1024         // NMS threads per block
#define NW (NT / 64)
#define EPT 9           // ceil(NA / NT)
#define NBINS 4096      // histogram bins on key[31:20]
#define CAP 512         // candidate buffer (giant-bin overflow safety)
#define WTGT 256u       // window target size (sort usually runs at 256)

#define DGROUPS 132     // 64-anchor groups per image: 100 (L0) + 25 (L1) + 7 (L2)

__device__ __forceinline__ float stable_sigmoid(float x) {
    if (x >= 0.f) return 1.f / (1.f + expf(-x));
    float e = expf(x);
    return e / (1.f + e);
}

// ---------------- decode: one 256-thread block per 64 anchors (r7-EXACT) ----
// Wave w scans channels [20w, 20w+20) for the block's 64 consecutive anchors:
// every load is uniform-base + lane*4 -> ONE 256B contiguous segment per wave
// instruction. Per-wave (max, argmax) in registers with strict '>' (first
// max); 2KB LDS merge in ascending wave order -> exact jnp.argmax semantics.
// Wave 0 runs the reg/obj/box epilogue with unit-stride loads/stores.
// No atomics, no function tails (r4 regalloc lesson), no store->reload (r3).
template<int HW, int W, int S>
__device__ __forceinline__ void decode_blk(
    const float* __restrict__ cls, const float* __restrict__ reg,
    const float* __restrict__ obj, int b, int p0, int w, int lane, int ag0,
    float (*s_m)[64], int (*s_c)[64],
    float4* __restrict__ wboxes, int* __restrict__ wlabels, uint* __restrict__ wkeys)
{
    int p = p0 + lane;
    bool valid = (p < HW);            // only the last L2 group has invalid lanes
    int pc = valid ? p : (HW - 1);    // clamped for safe (dup) loads

    const float* cbase = cls + (size_t)b * NC * HW + (size_t)(w * 20) * HW + pc;
    float v[20];
    #pragma unroll
    for (int i = 0; i < 20; ++i) v[i] = cbase[(size_t)i * HW];
    float m = v[0]; int c = 0;
    #pragma unroll
    for (int i = 1; i < 20; ++i)
        if (v[i] > m) { m = v[i]; c = i; }     // strict > -> first max in slice

    s_m[w][lane] = m;
    s_c[w][lane] = c + w * 20;
    __syncthreads();

    if (w == 0) {
        float mm = s_m[0][lane]; int cc = s_c[0][lane];
        #pragma unroll
        for (int ww = 1; ww < 4; ++ww) {
            float om = s_m[ww][lane]; int oc = s_c[ww][lane];
            if (om > mm) { mm = om; cc = oc; } // strict > keeps lowest channel
        }
        const float* rb = reg + (size_t)b * 4 * HW + pc;
        float r0 = rb[0];
        float r1 = rb[HW];
        float r2 = rb[2 * (size_t)HW];
        float r3 = rb[3 * (size_t)HW];
        float ov = obj[(size_t)b * HW + pc];

        int y = pc / W;               // W constexpr -> magic mul
        int x = pc - y * W;
        float sc = stable_sigmoid(mm) * stable_sigmoid(ov);
        float cx = r0 * (float)S + (float)x * (float)S;
        float cy = r1 * (float)S + (float)y * (float)S;
        float bw = expf(r2) * (float)S;
        float bh = expf(r3) * (float)S;

        if (valid) {
            int ag = ag0 + lane;
            wboxes[ag]  = make_float4(cx - bw * 0.5f, cy - bh * 0.5f,
                                      cx + bw * 0.5f, cy + bh * 0.5f);
            wlabels[ag] = cc;
            wkeys[ag]   = (sc >= SCTHR) ? ~__float_as_uint(sc) : 0xFFFFFFFFu;
        }
    }
}

__global__ __launch_bounds__(256) void decode_kernel(
    const float* __restrict__ cls0, const float* __restrict__ reg0, const float* __restrict__ obj0,
    const float* __restrict__ cls1, const float* __restrict__ reg1, const float* __restrict__ obj1,
    const float* __restrict__ cls2, const float* __restrict__ reg2, const float* __restrict__ obj2,
    float4* __restrict__ wboxes, int* __restrict__ wlabels, uint* __restrict__ wkeys)
{
    __shared__ float s_m[4][64];
    __shared__ int   s_c[4][64];

    int bid  = blockIdx.x;            // BATCH * DGROUPS blocks
    int b    = bid / DGROUPS;         // literal divisor -> magic mul
    int g    = bid - b * DGROUPS;
    int t    = threadIdx.x;
    int w    = t >> 6;
    int lane = t & 63;

    if (g < 100) {
        int p0 = g * 64;
        decode_blk<6400, 80, 8>(cls0, reg0, obj0, b, p0, w, lane,
                                b * NA + p0, s_m, s_c, wboxes, wlabels, wkeys);
    } else if (g < 125) {
        int p0 = (g - 100) * 64;
        decode_blk<1600, 40, 16>(cls1, reg1, obj1, b, p0, w, lane,
                                 b * NA + 6400 + p0, s_m, s_c, wboxes, wlabels, wkeys);
    } else {
        int p0 = (g - 125) * 64;
        decode_blk<400, 20, 32>(cls2, reg2, obj2, b, p0, w, lane,
                                b * NA + 8000 + p0, s_m, s_c, wboxes, wlabels, wkeys);
    }
}

// ---------------- NMS via sorted walk (r9 + window-target sort shrink) -----
// vs r9 (48.1 us), ONE change: the winhi predicate targets WTGT=256
// candidates per window (buffer stays CAP=512 for the giant-bin clamp), and
// the bitonic sort runs at dynamic size ssz = nsel<=256 ? 256 : 512.
// Typical window -> 256-sort: 36 passes / 3 barriered LDS passes instead of
// 45 / 6. Multi-window exactness preserved by construction (descending-bin
// windows, kept set carried across). Walk/sweeps/scan byte-identical to r9.
__global__ __launch_bounds__(NT) void nms_kernel(
    const float4* __restrict__ wboxes, const int* __restrict__ wlabels,
    const uint* __restrict__ wkeys, float* __restrict__ out)
{
    int b = blockIdx.x;
    int t = threadIdx.x;
    int lane = t & 63;
    int wv = t >> 6;
    const float4* boxes  = wboxes  + (size_t)b * NA;
    const int*    labels = wlabels + (size_t)b * NA;
    const uint*   keys   = wkeys   + (size_t)b * NA;

    __shared__ uint   s_hist[NBINS];
    __shared__ uint   s_cum[NBINS + 1];    // exclusive prefix
    __shared__ uint   s_wsum[NW];
    __shared__ ull    s_skey[CAP];
    __shared__ float4 s_cbox[CAP];         // candidate OFFSET boxes (prefetched)
    __shared__ float  s_ca[CAP];           // candidate offset-box areas
    __shared__ int    s_clb[CAP];          // candidate labels
    __shared__ float  s_kbox[MAXDET][4];   // kept OFFSET boxes
    __shared__ float  s_ka1[MAXDET];
    __shared__ int    s_kidx[MAXDET];
    __shared__ float  s_kscr[MAXDET];
    __shared__ int    s_klab[MAXDET];
    __shared__ float  s_red[NW];
    __shared__ float  s_off;
    __shared__ int    s_kept, s_winlo, s_winhi, s_nsel;

    // ---- zero hist; FUSED sweep: max|coord| + key histogram + key cache ----
    for (int i = t; i < NBINS; i += NT) s_hist[i] = 0;
    if (t == 0) { s_kept = 0; s_winlo = 0; }
    __syncthreads();
    float m = 0.f;
    uint kreg[EPT];                        // per-thread key cache (const-indexed)
    #pragma unroll
    for (int w = 0; w < EPT; ++w) {
        int e = t + w * NT;
        kreg[w] = 0xFFFFFFFFu;
        if (e < NA) {
            float4 v = boxes[e];
            m = fmaxf(m, fmaxf(fmaxf(fabsf(v.x), fabsf(v.y)),
                               fmaxf(fabsf(v.z), fabsf(v.w))));
            uint k = keys[e];
            kreg[w] = k;
            if (k != 0xFFFFFFFFu) atomicAdd(&s_hist[k >> 20], 1u);
        }
    }
    #pragma unroll
    for (int o = 32; o >= 1; o >>= 1) m = fmaxf(m, __shfl_xor(m, o));
    if (lane == 0) s_red[wv] = m;
    __syncthreads();
    if (t == 0) {
        float mm = 0.f;
        for (int w = 0; w < NW; ++w) mm = fmaxf(mm, s_red[w]);
        s_off = mm + 1.f;
    }

    // ---- exclusive scan over 4096 bins: 4 bins/thread + shfl scans ----
    uint l0 = s_hist[4 * t], l1 = s_hist[4 * t + 1],
         l2 = s_hist[4 * t + 2], l3 = s_hist[4 * t + 3];
    uint L = l0 + l1 + l2 + l3;
    uint ls = L;
    #pragma unroll
    for (int o = 1; o < 64; o <<= 1) {
        uint v = __shfl_up(ls, o);
        if (lane >= o) ls += v;
    }
    if (lane == 63) s_wsum[wv] = ls;
    __syncthreads();
    if (t < NW) {
        uint v = s_wsum[t];
        uint vs = v;
        #pragma unroll
        for (int o = 1; o < NW; o <<= 1) {
            uint u = __shfl_up(vs, o);
            if ((t & 63) >= o) vs += u;
        }
        s_wsum[t] = vs - v;
    }
    __syncthreads();
    uint base = s_wsum[wv] + (ls - L);
    s_cum[4 * t]     = base;
    s_cum[4 * t + 1] = base + l0;
    s_cum[4 * t + 2] = base + l0 + l1;
    s_cum[4 * t + 3] = base + l0 + l1 + l2;
    if (t == NT - 1) s_cum[NBINS] = base + L;
    float off;

    // ---- window loop (typically runs once) ----
    for (;;) {
        __syncthreads();
        int kept = s_kept, winlo = s_winlo;
        uint remaining = s_cum[NBINS] - s_cum[winlo];
        if (kept >= MAXDET || winlo >= NBINS || remaining == 0u) break;
        if (t == 0) { s_winhi = winlo + 1; s_nsel = 0; }   // giant-bin clamp floor
        if (t < CAP) s_skey[t] = ~0ull;
        __syncthreads();
        // winhi via unique-boundary store: pred(i) = cum[i+1]-cl <= WTGT is
        // monotone non-increasing in i, so exactly one i has pred(i) && !pred(i+1).
        uint cl = s_cum[winlo];
        #pragma unroll
        for (int q = 0; q < 4; ++q) {
            int i = t + q * NT;
            if (i >= winlo && i < NBINS) {
                bool p0 = (s_cum[i + 1] - cl) <= WTGT;
                bool p1 = (i + 1 < NBINS) && ((s_cum[i + 2] - cl) <= WTGT);
                if (p0 && !p1) s_winhi = i + 1;   // unique writer
            }
        }
        __syncthreads();
        int winhi = s_winhi;

        // wave-aggregated compaction of window candidates (keys from REGISTERS)
        #pragma unroll
        for (int w = 0; w < EPT; ++w) {
            int e = t + w * NT;
            uint k = kreg[w];
            bool q = false;
            if (k != 0xFFFFFFFFu) {
                int bin = (int)(k >> 20);
                q = (bin >= winlo && bin < winhi);
            }
            ull mask = __ballot(q);
            if (mask) {
                int leader = __ffsll(mask) - 1;
                int pbase = 0;
                if (lane == leader) pbase = atomicAdd(&s_nsel, __popcll(mask));
                pbase = __shfl(pbase, leader);
                if (q) {
                    int pos = pbase + __popcll(mask & ((1ull << lane) - 1ull));
                    if (pos < CAP) s_skey[pos] = ((ull)k << 32) | (uint)e;
                }
            }
        }
        __syncthreads();
        int nsel = s_nsel; if (nsel > CAP) nsel = CAP;
        int ssz = (nsel <= 256) ? 256 : CAP;   // dynamic sort width (uniform)

        // hybrid bitonic sort of ssz ull keys ascending: j<64 passes are
        // intra-wave shfl_xor (no barrier); j>=64 via LDS (barriered).
        ull k = (t < ssz) ? s_skey[t] : ~0ull;
        for (int k2 = 2; k2 <= ssz; k2 <<= 1) {
            for (int j = k2 >> 1; j > 0; j >>= 1) {
                if (j >= 64) {
                    if (t < ssz) s_skey[t] = k;
                    __syncthreads();
                    if (t < ssz) {
                        ull kp = s_skey[t ^ j];
                        bool low = (t & j) == 0;
                        bool up  = (t & k2) == 0;
                        k = ((k < kp) == (low == up)) ? k : kp;
                    }
                    __syncthreads();
                } else if (t < ssz) {
                    ull kp = __shfl_xor(k, j);
                    bool low = (t & j) == 0;
                    bool up  = (t & k2) == 0;
                    k = ((k < kp) == (low == up)) ? k : kp;
                }
            }
        }
        if (t < ssz) s_skey[t] = k;
        __syncthreads();

        // parallel candidate prefetch: scattered global reads done ONCE by
        // all 1024 threads; the serial walk below touches only LDS.
        off = s_off;
        if (t < nsel) {
            ull sk = s_skey[t];
            if (sk != ~0ull) {
                int idx = (int)(sk & 0xFFFFFFFFull);
                float4 rb = boxes[idx];
                int lb = labels[idx];
                float lo = (float)lb * off;
                float c0 = rb.x + lo, c1 = rb.y + lo;
                float c2 = rb.z + lo, c3 = rb.w + lo;
                s_cbox[t] = make_float4(c0, c1, c2, c3);
                s_ca[t]   = (c2 - c0) * (c3 - c1);
                s_clb[t]  = lb;
            }
        }
        __syncthreads();

        // sorted walk on wave 0 (r5-EXACT: per-accept IoU + shfl broadcast)
        if (t < 64) {
            int kept2 = s_kept;
            for (int cb = 0; cb < nsel && kept2 < MAXDET; cb += 64) {
                int ci = cb + lane;
                ull sk = (ci < nsel) ? s_skey[ci] : ~0ull;
                bool has = (sk != ~0ull);
                int idx = 0, lab = 0;
                float sc = 0.f, c0 = 0.f, c1 = 0.f, c2 = 0.f, c3 = 0.f, ca = 0.f;
                if (has) {
                    idx = (int)(sk & 0xFFFFFFFFull);
                    sc  = __uint_as_float(~(uint)(sk >> 32));   // exact score bits
                    float4 cbx = s_cbox[ci];
                    c0 = cbx.x; c1 = cbx.y; c2 = cbx.z; c3 = cbx.w;
                    ca = s_ca[ci];
                    lab = s_clb[ci];
                    for (int q = 0; q < kept2; ++q) {
                        float tlx = fmaxf(s_kbox[q][0], c0);
                        float tly = fmaxf(s_kbox[q][1], c1);
                        float brx = fminf(s_kbox[q][2], c2);
                        float bry = fminf(s_kbox[q][3], c3);
                        float ww = fmaxf(brx - tlx, 0.f);
                        float hh = fmaxf(bry - tly, 0.f);
                        float inter = ww * hh;
                        float iou = inter / (s_ka1[q] + ca - inter + 1e-6f);
                        if (iou > NMSTHR) { has = false; break; }
                    }
                }
                ull am = __ballot(has);
                while (am && kept2 < MAXDET) {
                    int f = __ffsll(am) - 1;
                    float f0 = __shfl(c0, f), f1 = __shfl(c1, f);
                    float f2 = __shfl(c2, f), f3 = __shfl(c3, f);
                    float fa = __shfl(ca, f);
                    int   fidx = __shfl(idx, f);
                    int   flab = __shfl(lab, f);
                    float fsc  = __shfl(sc, f);
                    if (lane == 0) {
                        s_kbox[kept2][0] = f0; s_kbox[kept2][1] = f1;
                        s_kbox[kept2][2] = f2; s_kbox[kept2][3] = f3;
                        s_ka1[kept2] = fa; s_kidx[kept2] = fidx;
                        s_kscr[kept2] = fsc; s_klab[kept2] = flab;
                    }
                    kept2++;
                    if (lane == f) has = false;
                    if (has) {
                        float tlx = fmaxf(f0, c0), tly = fmaxf(f1, c1);
                        float brx = fminf(f2, c2), bry = fminf(f3, c3);
                        float ww = fmaxf(brx - tlx, 0.f), hh = fmaxf(bry - tly, 0.f);
                        float inter = ww * hh;
                        float iou = inter / (fa + ca - inter + 1e-6f);
                        if (iou > NMSTHR) has = false;
                    }
                    am = __ballot(has);
                }
            }
            if (lane == 0) s_kept = kept2;
        }
        __syncthreads();
        if (t == 0) s_winlo = s_winhi;
    }
    __syncthreads();

    // ---- epilogue: boxes/scores/labels/valid (fp32) ----
    if (t < MAXDET) {
        int kept = s_kept;
        float4 obx = make_float4(0.f, 0.f, 0.f, 0.f);
        float osc = 0.f, olab = -1.f, oval = 0.f;
        if (t < kept) {
            int idx = s_kidx[t];
            obx  = boxes[idx];              // raw (non-offset) box
            osc  = s_kscr[t];
            olab = (float)s_klab[t];
            oval = 1.f;
        }
        float* ob = out + ((size_t)b * MAXDET + t) * 4;
        ob[0] = obx.x; ob[1] = obx.y; ob[2] = obx.z; ob[3] = obx.w;
        out[BATCH * MAXDET * 4 + b * MAXDET + t] = osc;
        out[BATCH * MAXDET * 5 + b * MAXDET + t] = olab;
        out[BATCH * MAXDET * 6 + b * MAXDET + t] = oval;
    }
}

extern "C" void kernel_launch(void* const* d_in, const int* in_sizes, int n_in,
                              void* d_out, int out_size, void* d_ws, size_t ws_size,
                              hipStream_t stream) {
    // setup_inputs() dict order: cls0, reg0, obj0, cls1, reg1, obj1, cls2, reg2, obj2
    const float* cls0 = (const float*)d_in[0];
    const float* reg0 = (const float*)d_in[1];
    const float* obj0 = (const float*)d_in[2];
    const float* cls1 = (const float*)d_in[3];
    const float* reg1 = (const float*)d_in[4];
    const float* obj1 = (const float*)d_in[5];
    const float* cls2 = (const float*)d_in[6];
    const float* reg2 = (const float*)d_in[7];
    const float* obj2 = (const float*)d_in[8];

    // ws layout: boxes | labels | keys
    char* ws = (char*)d_ws;
    size_t nBA = (size_t)BATCH * NA;
    float4* wboxes  = (float4*)ws;
    int*    wlabels = (int*)(ws + nBA * 16);
    uint*   wkeys   = (uint*)(ws + nBA * 20);

    decode_kernel<<<BATCH * DGROUPS, 256, 0, stream>>>(
        cls0, reg0, obj0, cls1, reg1, obj1, cls2, reg2, obj2,
        wboxes, wlabels, wkeys);

    nms_kernel<<<BATCH, NT, 0, stream>>>(wboxes, wlabels, wkeys, (float*)d_out);
}

// Round 11
// 161.005 us; speedup vs baseline: 1.0624x; 1.0130x over previous
//
#include <hip/hip_runtime.h>
#include <cmath>

typedef unsigned int uint;
typedef unsigned long long ull;

#define BATCH 32
#define NA 8400
#define NC 80
#define MAXDET 100
#define NMSTHR 0.65f
#define SCTHR 0.01f

#define NT 1024         // NMS threads per block
#define NW (NT / 64)
#define EPT 9           // ceil(NA / NT)
#define NBINS 4096      // histogram bins on key[31:20]
#define CAP 512         // candidate buffer (giant-bin overflow safety)
#define WTGT 256u       // window target size

#define DGROUPS 132     // 64-anchor groups per image: 100 (L0) + 25 (L1) + 7 (L2)

__device__ __forceinline__ float stable_sigmoid(float x) {
    if (x >= 0.f) return 1.f / (1.f + expf(-x));
    float e = expf(x);
    return e / (1.f + e);
}

// ---------------- decode: one 256-thread block per 64 anchors (r7-EXACT) ----
// Wave w scans channels [20w, 20w+20) for the block's 64 consecutive anchors:
// every load is uniform-base + lane*4 -> ONE 256B contiguous segment per wave
// instruction. Per-wave (max, argmax) in registers with strict '>' (first
// max); 2KB LDS merge in ascending wave order -> exact jnp.argmax semantics.
// Wave 0 runs the reg/obj/box epilogue with unit-stride loads/stores.
// No atomics, no function tails (r4 regalloc lesson), no store->reload (r3).
template<int HW, int W, int S>
__device__ __forceinline__ void decode_blk(
    const float* __restrict__ cls, const float* __restrict__ reg,
    const float* __restrict__ obj, int b, int p0, int w, int lane, int ag0,
    float (*s_m)[64], int (*s_c)[64],
    float4* __restrict__ wboxes, int* __restrict__ wlabels, uint* __restrict__ wkeys)
{
    int p = p0 + lane;
    bool valid = (p < HW);            // only the last L2 group has invalid lanes
    int pc = valid ? p : (HW - 1);    // clamped for safe (dup) loads

    const float* cbase = cls + (size_t)b * NC * HW + (size_t)(w * 20) * HW + pc;
    float v[20];
    #pragma unroll
    for (int i = 0; i < 20; ++i) v[i] = cbase[(size_t)i * HW];
    float m = v[0]; int c = 0;
    #pragma unroll
    for (int i = 1; i < 20; ++i)
        if (v[i] > m) { m = v[i]; c = i; }     // strict > -> first max in slice

    s_m[w][lane] = m;
    s_c[w][lane] = c + w * 20;
    __syncthreads();

    if (w == 0) {
        float mm = s_m[0][lane]; int cc = s_c[0][lane];
        #pragma unroll
        for (int ww = 1; ww < 4; ++ww) {
            float om = s_m[ww][lane]; int oc = s_c[ww][lane];
            if (om > mm) { mm = om; cc = oc; } // strict > keeps lowest channel
        }
        const float* rb = reg + (size_t)b * 4 * HW + pc;
        float r0 = rb[0];
        float r1 = rb[HW];
        float r2 = rb[2 * (size_t)HW];
        float r3 = rb[3 * (size_t)HW];
        float ov = obj[(size_t)b * HW + pc];

        int y = pc / W;               // W constexpr -> magic mul
        int x = pc - y * W;
        float sc = stable_sigmoid(mm) * stable_sigmoid(ov);
        float cx = r0 * (float)S + (float)x * (float)S;
        float cy = r1 * (float)S + (float)y * (float)S;
        float bw = expf(r2) * (float)S;
        float bh = expf(r3) * (float)S;

        if (valid) {
            int ag = ag0 + lane;
            wboxes[ag]  = make_float4(cx - bw * 0.5f, cy - bh * 0.5f,
                                      cx + bw * 0.5f, cy + bh * 0.5f);
            wlabels[ag] = cc;
            wkeys[ag]   = (sc >= SCTHR) ? ~__float_as_uint(sc) : 0xFFFFFFFFu;
        }
    }
}

__global__ __launch_bounds__(256) void decode_kernel(
    const float* __restrict__ cls0, const float* __restrict__ reg0, const float* __restrict__ obj0,
    const float* __restrict__ cls1, const float* __restrict__ reg1, const float* __restrict__ obj1,
    const float* __restrict__ cls2, const float* __restrict__ reg2, const float* __restrict__ obj2,
    float4* __restrict__ wboxes, int* __restrict__ wlabels, uint* __restrict__ wkeys)
{
    __shared__ float s_m[4][64];
    __shared__ int   s_c[4][64];

    int bid  = blockIdx.x;            // BATCH * DGROUPS blocks
    int b    = bid / DGROUPS;         // literal divisor -> magic mul
    int g    = bid - b * DGROUPS;
    int t    = threadIdx.x;
    int w    = t >> 6;
    int lane = t & 63;

    if (g < 100) {
        int p0 = g * 64;
        decode_blk<6400, 80, 8>(cls0, reg0, obj0, b, p0, w, lane,
                                b * NA + p0, s_m, s_c, wboxes, wlabels, wkeys);
    } else if (g < 125) {
        int p0 = (g - 100) * 64;
        decode_blk<1600, 40, 16>(cls1, reg1, obj1, b, p0, w, lane,
                                 b * NA + 6400 + p0, s_m, s_c, wboxes, wlabels, wkeys);
    } else {
        int p0 = (g - 125) * 64;
        decode_blk<400, 20, 32>(cls2, reg2, obj2, b, p0, w, lane,
                                b * NA + 8000 + p0, s_m, s_c, wboxes, wlabels, wkeys);
    }
}

// ---------------- NMS via sorted walk (r10 + rank-sort + 5-shfl walk) ------
// vs r10 (45.6 us), two serial-chain cuts:
// (1) the 36-pass bitonic (6 barriered LDS passes) is replaced by an O(n)
//     rank-placement sort: keys are totally ordered (anchor idx in the low
//     32 bits), so sorted position = count of smaller keys. Uniform LDS
//     broadcast loop + ONE barrier + scatter write. Identical ordering
//     (ascending ull = descending score, ties -> lower index).
// (2) accept loop: 5 shfls (f0-f3, fa for the retest) instead of 8; lane f
//     writes all kept arrays directly from its own registers.
__global__ __launch_bounds__(NT) void nms_kernel(
    const float4* __restrict__ wboxes, const int* __restrict__ wlabels,
    const uint* __restrict__ wkeys, float* __restrict__ out)
{
    int b = blockIdx.x;
    int t = threadIdx.x;
    int lane = t & 63;
    int wv = t >> 6;
    const float4* boxes  = wboxes  + (size_t)b * NA;
    const int*    labels = wlabels + (size_t)b * NA;
    const uint*   keys   = wkeys   + (size_t)b * NA;

    __shared__ uint   s_hist[NBINS];
    __shared__ uint   s_cum[NBINS + 1];    // exclusive prefix
    __shared__ uint   s_wsum[NW];
    __shared__ ull    s_skey[CAP];
    __shared__ float4 s_cbox[CAP];         // candidate OFFSET boxes (prefetched)
    __shared__ float  s_ca[CAP];           // candidate offset-box areas
    __shared__ int    s_clb[CAP];          // candidate labels
    __shared__ float  s_kbox[MAXDET][4];   // kept OFFSET boxes
    __shared__ float  s_ka1[MAXDET];
    __shared__ int    s_kidx[MAXDET];
    __shared__ float  s_kscr[MAXDET];
    __shared__ int    s_klab[MAXDET];
    __shared__ float  s_red[NW];
    __shared__ float  s_off;
    __shared__ int    s_kept, s_winlo, s_winhi, s_nsel;

    // ---- zero hist; FUSED sweep: max|coord| + key histogram + key cache ----
    for (int i = t; i < NBINS; i += NT) s_hist[i] = 0;
    if (t == 0) { s_kept = 0; s_winlo = 0; }
    __syncthreads();
    float m = 0.f;
    uint kreg[EPT];                        // per-thread key cache (const-indexed)
    #pragma unroll
    for (int w = 0; w < EPT; ++w) {
        int e = t + w * NT;
        kreg[w] = 0xFFFFFFFFu;
        if (e < NA) {
            float4 v = boxes[e];
            m = fmaxf(m, fmaxf(fmaxf(fabsf(v.x), fabsf(v.y)),
                               fmaxf(fabsf(v.z), fabsf(v.w))));
            uint k = keys[e];
            kreg[w] = k;
            if (k != 0xFFFFFFFFu) atomicAdd(&s_hist[k >> 20], 1u);
        }
    }
    #pragma unroll
    for (int o = 32; o >= 1; o >>= 1) m = fmaxf(m, __shfl_xor(m, o));
    if (lane == 0) s_red[wv] = m;
    __syncthreads();
    if (t == 0) {
        float mm = 0.f;
        for (int w = 0; w < NW; ++w) mm = fmaxf(mm, s_red[w]);
        s_off = mm + 1.f;
    }

    // ---- exclusive scan over 4096 bins: 4 bins/thread + shfl scans ----
    uint l0 = s_hist[4 * t], l1 = s_hist[4 * t + 1],
         l2 = s_hist[4 * t + 2], l3 = s_hist[4 * t + 3];
    uint L = l0 + l1 + l2 + l3;
    uint ls = L;
    #pragma unroll
    for (int o = 1; o < 64; o <<= 1) {
        uint v = __shfl_up(ls, o);
        if (lane >= o) ls += v;
    }
    if (lane == 63) s_wsum[wv] = ls;
    __syncthreads();
    if (t < NW) {
        uint v = s_wsum[t];
        uint vs = v;
        #pragma unroll
        for (int o = 1; o < NW; o <<= 1) {
            uint u = __shfl_up(vs, o);
            if ((t & 63) >= o) vs += u;
        }
        s_wsum[t] = vs - v;
    }
    __syncthreads();
    uint base = s_wsum[wv] + (ls - L);
    s_cum[4 * t]     = base;
    s_cum[4 * t + 1] = base + l0;
    s_cum[4 * t + 2] = base + l0 + l1;
    s_cum[4 * t + 3] = base + l0 + l1 + l2;
    if (t == NT - 1) s_cum[NBINS] = base + L;
    float off;

    // ---- window loop (typically runs once) ----
    for (;;) {
        __syncthreads();
        int kept = s_kept, winlo = s_winlo;
        uint remaining = s_cum[NBINS] - s_cum[winlo];
        if (kept >= MAXDET || winlo >= NBINS || remaining == 0u) break;
        if (t == 0) { s_winhi = winlo + 1; s_nsel = 0; }   // giant-bin clamp floor
        if (t < CAP) s_skey[t] = ~0ull;
        __syncthreads();
        // winhi via unique-boundary store: pred(i) = cum[i+1]-cl <= WTGT is
        // monotone non-increasing in i, so exactly one i has pred(i) && !pred(i+1).
        uint cl = s_cum[winlo];
        #pragma unroll
        for (int q = 0; q < 4; ++q) {
            int i = t + q * NT;
            if (i >= winlo && i < NBINS) {
                bool p0 = (s_cum[i + 1] - cl) <= WTGT;
                bool p1 = (i + 1 < NBINS) && ((s_cum[i + 2] - cl) <= WTGT);
                if (p0 && !p1) s_winhi = i + 1;   // unique writer
            }
        }
        __syncthreads();
        int winhi = s_winhi;

        // wave-aggregated compaction of window candidates (keys from REGISTERS)
        #pragma unroll
        for (int w = 0; w < EPT; ++w) {
            int e = t + w * NT;
            uint k = kreg[w];
            bool q = false;
            if (k != 0xFFFFFFFFu) {
                int bin = (int)(k >> 20);
                q = (bin >= winlo && bin < winhi);
            }
            ull mask = __ballot(q);
            if (mask) {
                int leader = __ffsll(mask) - 1;
                int pbase = 0;
                if (lane == leader) pbase = atomicAdd(&s_nsel, __popcll(mask));
                pbase = __shfl(pbase, leader);
                if (q) {
                    int pos = pbase + __popcll(mask & ((1ull << lane) - 1ull));
                    if (pos < CAP) s_skey[pos] = ((ull)k << 32) | (uint)e;
                }
            }
        }
        __syncthreads();
        int nsel = s_nsel; if (nsel > CAP) nsel = CAP;

        // O(n) rank-placement sort (replaces the 36-pass bitonic):
        // thread t<nsel counts keys smaller than its own via a UNIFORM LDS
        // broadcast loop (total order guaranteed by embedded anchor idx),
        // one barrier, then scatter-writes its key to its rank.
        ull myk = (t < nsel) ? s_skey[t] : ~0ull;
        int rank = 0;
        if (t < nsel) {
            for (int j = 0; j < nsel; ++j)
                rank += (s_skey[j] < myk) ? 1 : 0;
        }
        __syncthreads();
        if (t < nsel) s_skey[rank] = myk;
        __syncthreads();

        // parallel candidate prefetch: scattered global reads done ONCE by
        // all 1024 threads; the serial walk below touches only LDS.
        off = s_off;
        if (t < nsel) {
            ull sk = s_skey[t];
            if (sk != ~0ull) {
                int idx = (int)(sk & 0xFFFFFFFFull);
                float4 rb = boxes[idx];
                int lb = labels[idx];
                float lo = (float)lb * off;
                float c0 = rb.x + lo, c1 = rb.y + lo;
                float c2 = rb.z + lo, c3 = rb.w + lo;
                s_cbox[t] = make_float4(c0, c1, c2, c3);
                s_ca[t]   = (c2 - c0) * (c3 - c1);
                s_clb[t]  = lb;
            }
        }
        __syncthreads();

        // sorted walk on wave 0 (per-accept IoU; 5 shfls + lane-f writes)
        if (t < 64) {
            int kept2 = s_kept;
            for (int cb = 0; cb < nsel && kept2 < MAXDET; cb += 64) {
                int ci = cb + lane;
                ull sk = (ci < nsel) ? s_skey[ci] : ~0ull;
                bool has = (sk != ~0ull);
                int idx = 0, lab = 0;
                float sc = 0.f, c0 = 0.f, c1 = 0.f, c2 = 0.f, c3 = 0.f, ca = 0.f;
                if (has) {
                    idx = (int)(sk & 0xFFFFFFFFull);
                    sc  = __uint_as_float(~(uint)(sk >> 32));   // exact score bits
                    float4 cbx = s_cbox[ci];
                    c0 = cbx.x; c1 = cbx.y; c2 = cbx.z; c3 = cbx.w;
                    ca = s_ca[ci];
                    lab = s_clb[ci];
                    for (int q = 0; q < kept2; ++q) {
                        float tlx = fmaxf(s_kbox[q][0], c0);
                        float tly = fmaxf(s_kbox[q][1], c1);
                        float brx = fminf(s_kbox[q][2], c2);
                        float bry = fminf(s_kbox[q][3], c3);
                        float ww = fmaxf(brx - tlx, 0.f);
                        float hh = fmaxf(bry - tly, 0.f);
                        float inter = ww * hh;
                        float iou = inter / (s_ka1[q] + ca - inter + 1e-6f);
                        if (iou > NMSTHR) { has = false; break; }
                    }
                }
                ull am = __ballot(has);
                while (am && kept2 < MAXDET) {
                    int f = __ffsll(am) - 1;
                    float f0 = __shfl(c0, f), f1 = __shfl(c1, f);
                    float f2 = __shfl(c2, f), f3 = __shfl(c3, f);
                    float fa = __shfl(ca, f);
                    if (lane == f) {
                        s_kbox[kept2][0] = c0; s_kbox[kept2][1] = c1;
                        s_kbox[kept2][2] = c2; s_kbox[kept2][3] = c3;
                        s_ka1[kept2] = ca; s_kidx[kept2] = idx;
                        s_kscr[kept2] = sc; s_klab[kept2] = lab;
                        has = false;
                    }
                    kept2++;
                    if (has) {
                        float tlx = fmaxf(f0, c0), tly = fmaxf(f1, c1);
                        float brx = fminf(f2, c2), bry = fminf(f3, c3);
                        float ww = fmaxf(brx - tlx, 0.f), hh = fmaxf(bry - tly, 0.f);
                        float inter = ww * hh;
                        float iou = inter / (fa + ca - inter + 1e-6f);
                        if (iou > NMSTHR) has = false;
                    }
                    am = __ballot(has);
                }
            }
            if (lane == 0) s_kept = kept2;
        }
        __syncthreads();
        if (t == 0) s_winlo = s_winhi;
    }
    __syncthreads();

    // ---- epilogue: boxes/scores/labels/valid (fp32) ----
    if (t < MAXDET) {
        int kept = s_kept;
        float4 obx = make_float4(0.f, 0.f, 0.f, 0.f);
        float osc = 0.f, olab = -1.f, oval = 0.f;
        if (t < kept) {
            int idx = s_kidx[t];
            obx  = boxes[idx];              // raw (non-offset) box
            osc  = s_kscr[t];
            olab = (float)s_klab[t];
            oval = 1.f;
        }
        float* ob = out + ((size_t)b * MAXDET + t) * 4;
        ob[0] = obx.x; ob[1] = obx.y; ob[2] = obx.z; ob[3] = obx.w;
        out[BATCH * MAXDET * 4 + b * MAXDET + t] = osc;
        out[BATCH * MAXDET * 5 + b * MAXDET + t] = olab;
        out[BATCH * MAXDET * 6 + b * MAXDET + t] = oval;
    }
}

extern "C" void kernel_launch(void* const* d_in, const int* in_sizes, int n_in,
                              void* d_out, int out_size, void* d_ws, size_t ws_size,
                              hipStream_t stream) {
    // setup_inputs() dict order: cls0, reg0, obj0, cls1, reg1, obj1, cls2, reg2, obj2
    const float* cls0 = (const float*)d_in[0];
    const float* reg0 = (const float*)d_in[1];
    const float* obj0 = (const float*)d_in[2];
    const float* cls1 = (const float*)d_in[3];
    const float* reg1 = (const float*)d_in[4];
    const float* obj1 = (const float*)d_in[5];
    const float* cls2 = (const float*)d_in[6];
    const float* reg2 = (const float*)d_in[7];
    const float* obj2 = (const float*)d_in[8];

    // ws layout: boxes | labels | keys
    char* ws = (char*)d_ws;
    size_t nBA = (size_t)BATCH * NA;
    float4* wboxes  = (float4*)ws;
    int*    wlabels = (int*)(ws + nBA * 16);
    uint*   wkeys   = (uint*)(ws + nBA * 20);

    decode_kernel<<<BATCH * DGROUPS, 256, 0, stream>>>(
        cls0, reg0, obj0, cls1, reg1, obj1, cls2, reg2, obj2,
        wboxes, wlabels, wkeys);

    nms_kernel<<<BATCH, NT, 0, stream>>>(wboxes, wlabels, wkeys, (float*)d_out);
}